// Round 1
// baseline (542.917 us; speedup 1.0000x reference)
//
#include <hip/hip_runtime.h>

#define NG 64
#define KK 64
#define DIST 8
#define NNODES 50000
#define PTOT (NNODES*DIST)   // 400000 flattened rows
#define EPSV 0.1f
#define NITERS 20
#define STABV 1e-8f
#define CMAXV 1e6f

// ws layout (float-element offsets). ws is poisoned 0xAA before every call;
// everything below is written before it is read.
#define OFF_COUNTS 0                    // 64 i32
#define OFF_NNZ 64                      // 1 i32
#define OFF_NSUS 65                     // 1 i32
#define OFF_MAXY 66                     // 1 f32
#define OFF_NC2 67                      // 1 i32 (level-2 candidate count)
#define OFF_YN 128                      // 64 f32
#define OFF_C2P 192                     // PTOT i32 (level-2 candidate point id)
#define OFF_C2S (OFF_C2P + PTOT)        // PTOT f32 (level-1 subset norm)
#define OFF_SUS (OFF_C2S + PTOT)        // PTOT i32
#define OFF_ROWSEG (OFF_SUS + PTOT)     // PTOT i32
#define OFF_UC (OFF_ROWSEG + PTOT)      // PTOT f32
#define OFF_KROWS (OFF_UC + PTOT)       // cap*64 f32

__device__ __forceinline__ float dot4(float4 a, float4 b) {
  return fmaf(a.x, b.x, fmaf(a.y, b.y, fmaf(a.z, b.z, a.w * b.w)));
}

// Zero counters + codebook norms. Wave w, iter it exclusively owns k=4*it+w:
// coalesced cb read, butterfly reduce, no atomics.
__global__ __launch_bounds__(256) void init_kernel(const float* __restrict__ cb,
                                                   float* __restrict__ ws) {
  __shared__ float ynsh[KK];
  int t = threadIdx.x, w = t >> 6, l = t & 63;
  if (t < NG) ((int*)ws)[OFF_COUNTS + t] = 0;
  if (t == 0) {
    ((int*)ws)[OFF_NNZ] = 0; ((int*)ws)[OFF_NSUS] = 0; ((int*)ws)[OFF_NC2] = 0;
  }
  const float4* cb4 = (const float4*)cb;
#pragma unroll
  for (int it = 0; it < 16; it++) {
    float4 c = cb4[it * 256 + t];
    float e = dot4(c, c);
#pragma unroll
    for (int m = 1; m < 64; m <<= 1) e += __shfl_xor(e, m);
    if (l == 0) ynsh[it * 4 + w] = e;
  }
  __syncthreads();
  if (t < KK) {
    float yn = ynsh[t];
    ws[OFF_YN + t] = yn;
    float ym = sqrtf(yn);
#pragma unroll
    for (int m = 1; m < 64; m <<= 1) ym = fmaxf(ym, __shfl_xor(ym, m));
    if (t == 0) ws[OFF_MAXY] = ym;
  }
}

// Level-1 pass: per-graph counts + ONE 128-B line per point (32 elems).
// Certificate (exact): for ANY coordinate subset, S = sum x_i^2 <= ||x||^2,
// so cost(p,k) >= (sqrt(S) - max_k||y_k||)^2. fp32 exp(-cost/0.1) == 0.0
// whenever cost > 10.41; we demand certified cost > 12.96.
// Subset for point p = elems [32*(p&7), 32*(p&7)+32) -> line (p&7) of its
// 1 KB row: consecutive points cover all eight 128-B slots uniformly
// (channel-uniform diagonal), each load fully consumes its line.
// Failures (~15% for chi2(32) vs thr^2~23.8) go to the level-2 list.
__global__ __launch_bounds__(256) void pass1_kernel(const float* __restrict__ x,
    const int* __restrict__ bidx, float* __restrict__ ws) {
  __shared__ int hist[NG];
  __shared__ int cl_p[320];
  __shared__ float cl_s[320];
  __shared__ int cl_n;
  __shared__ int cl_base;
  int t = threadIdx.x, w = t >> 6, l = t & 63;
  int b = blockIdx.x;
  if (t < NG) hist[t] = 0;
  if (t == 0) cl_n = 0;
  __syncthreads();
  if (t < 40) atomicAdd(&hist[bidx[b * 40 + t] & 63], 1);
  __syncthreads();
  if (t < NG && hist[t] > 0) atomicAdd(&((int*)ws)[OFF_COUNTS + t], hist[t]);

  float maxy = ws[OFF_MAXY];
  float thr = fmaf(maxy, 1.0001f, 0.01f) + 3.6f;  // 3.6^2 = 12.96 > 10.41
  float thr2 = thr * thr;
  const float4* x4 = (const float4*)x;
  int g8 = l >> 3, sub = l & 7;           // 8 lanes per point
  int base = b * 320 + w * 80 + g8;       // point in round o: base + 8*o
  // base % 8 == g8, so this lane's point p has (p&7) == g8 -> line g8.
  float s[10];
#pragma unroll
  for (int o = 0; o < 10; o++) {
    int p = base + o * 8;
    float4 v = x4[(size_t)p * 64 + (g8 << 3) + sub];
    float e = dot4(v, v);
    e += __shfl_xor(e, 1); e += __shfl_xor(e, 2); e += __shfl_xor(e, 4);
    s[o] = e;
  }
  if (sub == 0) {
#pragma unroll
    for (int o = 0; o < 10; o++) {
      // NaN -> comparison false -> candidate. Inf -> >1e30 -> candidate.
      bool safe = (s[o] > thr2) && (s[o] < 1e30f);
      if (!safe) {
        int slot = atomicAdd(&cl_n, 1);   // LDS atomic, cheap
        cl_p[slot] = base + o * 8;
        cl_s[slot] = s[o];
      }
    }
  }
  __syncthreads();
  if (t == 0) cl_base = atomicAdd(&((int*)ws)[OFF_NC2], cl_n);  // 1 global atomic/block
  __syncthreads();
  int n = cl_n, cb0 = cl_base;
  for (int i = t; i < n; i += 256) {
    ((int*)ws)[OFF_C2P + cb0 + i] = cl_p[i];
    ws[OFF_C2S + cb0 + i] = cl_s[i];
  }
}

// Level-2: for each candidate read the NEXT (disjoint) 128-B line, test the
// combined 64-elem subset norm. Survivors (expected ~0) become suspects.
__global__ __launch_bounds__(256) void pass2_kernel(const float* __restrict__ x,
                                                    float* __restrict__ ws) {
  int t = threadIdx.x, w = t >> 6, l = t & 63;
  int g8 = l >> 3, sub = l & 7;
  int nc2 = ((int*)ws)[OFF_NC2];
  const int* c2p = &((int*)ws)[OFF_C2P];
  const float* c2s = ws + OFF_C2S;
  float maxy = ws[OFF_MAXY];
  float thr = fmaf(maxy, 1.0001f, 0.01f) + 3.6f;
  float thr2 = thr * thr;
  const float4* x4 = (const float4*)x;
  int gw = blockIdx.x * 4 + w, nw = gridDim.x * 4;
  for (int i0 = gw * 8; i0 < nc2; i0 += nw * 8) {
    int idx = i0 + g8;
    bool act = idx < nc2;
    int p = c2p[act ? idx : (nc2 - 1)];       // safe dummy for inactive groups
    int line = ((p & 7) + 1) & 7;             // disjoint from level-1's line
    float4 v = x4[(size_t)p * 64 + (line << 3) + sub];
    float e = dot4(v, v);
    e += __shfl_xor(e, 1); e += __shfl_xor(e, 2); e += __shfl_xor(e, 4);
    if (act && sub == 0) {
      float S = c2s[idx] + e;                 // 64 distinct elems <= ||x||^2
      bool safe = (S > thr2) && (S < 1e30f);
      if (!safe) {
        int slot = atomicAdd(&((int*)ws)[OFF_NSUS], 1);
        if (slot < PTOT) ((int*)ws)[OFF_SUS + slot] = p;
      }
    }
  }
}

// Exact fallback: full reference-semantics Kmat row for each suspect point;
// nonzero rows are compacted for the solver. Grid-strided; near-free when empty.
__global__ __launch_bounds__(256) void suspect2_kernel(const float* __restrict__ x,
    const int* __restrict__ bidx, const float* __restrict__ cb,
    float* __restrict__ ws, int cap) {
  int tid = threadIdx.x;
  int wave = tid >> 6, lane = tid & 63;
  int nsus = ((int*)ws)[OFF_NSUS];
  if (nsus > PTOT) nsus = PTOT;
  const int* sus = &((int*)ws)[OFF_SUS];
  const float4* x4 = (const float4*)x;
  const float4* cb4 = (const float4*)cb;
  int gw = blockIdx.x * 4 + wave, nw = gridDim.x * 4;
  for (int si = gw; si < nsus; si += nw) {
    int p = sus[si];
    float4 xv = x4[(size_t)p * 64 + lane];
    float xn = dot4(xv, xv);
#pragma unroll
    for (int m = 1; m < 64; m <<= 1) xn += __shfl_xor(xn, m);
    float myk = 0.0f;
    for (int k = 0; k < KK; k++) {
      float4 c = cb4[k * 64 + lane];
      float d = dot4(xv, c);
#pragma unroll
      for (int m = 1; m < 64; m <<= 1) d += __shfl_xor(d, m);
      float cost = fmaxf(xn + ws[OFF_YN + k] - 2.0f * d, 0.0f);
      float km = __expf(cost * (-1.0f / EPSV));
      if (!(km <= 1.0f)) km = STABV;  // NaN -> STAB, per reference
      if (lane == k) myk = km;
    }
    unsigned long long nz = __ballot(myk != 0.0f);
    if (nz != 0ull) {
      int slot = 0;
      if (lane == 0) slot = atomicAdd(&((int*)ws)[OFF_NNZ], 1);
      slot = __shfl(slot, 0);
      if (slot < cap) {
        (ws + OFF_KROWS)[(size_t)slot * 64 + lane] = myk;
        if (lane == 0) ((int*)ws)[OFF_ROWSEG + slot] = bidx[p >> 3];
      }
    }
  }
}

// Sinkhorn over compacted rows + epilogue. Skips the 20-iter loop when the
// compact set is empty (device-side branch; launch sequence is unchanged).
__global__ __launch_bounds__(256) void solve_kernel(float* __restrict__ ws,
                                                    float* __restrict__ out, int cap) {
  __shared__ float vsh[NG * KK];
  __shared__ float ash[NG * KK];
  __shared__ float tot[NG];
  __shared__ float ainv[NG];
  int tid = threadIdx.x;
  int wave = tid >> 6, lane = tid & 63;
  int nnz = ((int*)ws)[OFF_NNZ];
  if (nnz > cap) nnz = cap;
  const float* krows = ws + OFF_KROWS;
  const int* rowseg = &((int*)ws)[OFF_ROWSEG];
  const int* counts = &((int*)ws)[OFF_COUNTS];
  float* uc = ws + OFF_UC;

  if (tid < NG) ainv[tid] = 1.0f / fmaxf((float)(counts[tid] * DIST), 1.0f);
  for (int i = tid; i < NG * KK; i += 256) { vsh[i] = 1.0f; ash[i] = 0.0f; }
  __syncthreads();

  if (nnz > 0) {
    for (int it = 0; it < NITERS; it++) {
      for (int i = tid; i < NG * KK; i += 256) ash[i] = 0.0f;
      __syncthreads();
      for (int r = wave; r < nnz; r += 4) {
        int g = rowseg[r];
        float kw = krows[(size_t)r * 64 + lane];
        float kv = kw * vsh[(g << 6) | lane];
#pragma unroll
        for (int m = 1; m < 64; m <<= 1) kv += __shfl_xor(kv, m);
        float u = ainv[g] / fmaxf(kv, STABV);
        if (it == NITERS - 1 && lane == 0) uc[r] = u;
        atomicAdd(&ash[(g << 6) | lane], kw * u);
      }
      __syncthreads();
      for (int i = tid; i < NG * KK; i += 256)
        vsh[i] = (1.0f / KK) / fmaxf(ash[i], STABV);
      __syncthreads();
    }
    for (int i = tid; i < NG * KK; i += 256) ash[i] = 0.0f;
    __syncthreads();
    for (int r = wave; r < nnz; r += 4) {
      int g = rowseg[r];
      float kw = krows[(size_t)r * 64 + lane];
      float u = fminf(fmaxf(uc[r], STABV), CMAXV);
      atomicAdd(&ash[(g << 6) | lane], kw * u);
    }
    __syncthreads();
  }

  for (int i = tid; i < NG * KK; i += 256) {
    float vv = fminf(fmaxf(vsh[i], STABV), CMAXV);
    ash[i] = ash[i] * vv;
  }
  __syncthreads();
  if (tid < NG) {
    float s = 0.0f;
    for (int k = 0; k < KK; k++) s += ash[(tid << 6) + k];
    tot[tid] = s;
  }
  __syncthreads();
  for (int i = tid; i < NG * KK; i += 256) {
    int g = i >> 6;
    float val;
    if (counts[g] == 0) val = 0.0f;
    else if (tot[g] > STABV) val = ash[i] / fmaxf(tot[g], STABV);
    else val = 1.0f / KK;
    out[i] = val;
  }
}

extern "C" void kernel_launch(void* const* d_in, const int* in_sizes, int n_in,
                              void* d_out, int out_size, void* d_ws, size_t ws_size,
                              hipStream_t stream) {
  const float* x = (const float*)d_in[0];      // [50000,8,256] f32
  const int* bidx = (const int*)d_in[1];       // [50000] int32
  const float* cb = (const float*)d_in[2];     // [64,256] f32
  float* ws = (float*)d_ws;
  float* out = (float*)d_out;

  long cap_l = ((long)(ws_size / 4) - OFF_KROWS) / 64;
  if (cap_l < 0) cap_l = 0;
  if (cap_l > PTOT) cap_l = PTOT;
  int cap = (int)cap_l;

  init_kernel<<<1, 256, 0, stream>>>(cb, ws);
  pass1_kernel<<<NNODES / 40, 256, 0, stream>>>(x, bidx, ws);   // 1250 blocks
  pass2_kernel<<<128, 256, 0, stream>>>(x, ws);
  suspect2_kernel<<<64, 256, 0, stream>>>(x, bidx, cb, ws, cap);
  solve_kernel<<<1, 256, 0, stream>>>(ws, out, cap);
}

// Round 3
// 537.292 us; speedup vs baseline: 1.0105x; 1.0105x over previous
//
#include <hip/hip_runtime.h>

#define NG 64
#define KK 64
#define DIST 8
#define NNODES 50000
#define PTOT (NNODES*DIST)   // 400000 flattened rows
#define EPSV 0.1f
#define NITERS 20
#define STABV 1e-8f
#define CMAXV 1e6f

// ws layout (float-element offsets). ws is poisoned 0xAA before every call;
// everything below is written before it is read.
#define OFF_COUNTS 0                    // 64 i32
#define OFF_NNZ 64                      // 1 i32
#define OFF_NSUS 65                     // 1 i32
#define OFF_MAXY 66                     // 1 f32
#define OFF_YN 128                      // 64 f32
#define OFF_SUS 192                     // PTOT i32
#define OFF_ROWSEG (OFF_SUS + PTOT)     // PTOT i32
#define OFF_UC (OFF_ROWSEG + PTOT)      // PTOT f32
#define OFF_KROWS (OFF_UC + PTOT)       // cap*64 f32

__device__ __forceinline__ float dot4(float4 a, float4 b) {
  return fmaf(a.x, b.x, fmaf(a.y, b.y, fmaf(a.z, b.z, a.w * b.w)));
}

// Zero counters + codebook norms. Wave w, iter it exclusively owns k=4*it+w:
// coalesced cb read, butterfly reduce, no atomics.
__global__ __launch_bounds__(256) void init_kernel(const float* __restrict__ cb,
                                                   float* __restrict__ ws) {
  __shared__ float ynsh[KK];
  int t = threadIdx.x, w = t >> 6, l = t & 63;
  if (t < NG) ((int*)ws)[OFF_COUNTS + t] = 0;
  if (t == 0) { ((int*)ws)[OFF_NNZ] = 0; ((int*)ws)[OFF_NSUS] = 0; }
  const float4* cb4 = (const float4*)cb;
#pragma unroll
  for (int it = 0; it < 16; it++) {
    float4 c = cb4[it * 256 + t];
    float e = dot4(c, c);
#pragma unroll
    for (int m = 1; m < 64; m <<= 1) e += __shfl_xor(e, m);
    if (l == 0) ynsh[it * 4 + w] = e;
  }
  __syncthreads();
  if (t < KK) {
    float yn = ynsh[t];
    ws[OFF_YN + t] = yn;
    float ym = sqrtf(yn);
#pragma unroll
    for (int m = 1; m < 64; m <<= 1) ym = fmaxf(ym, __shfl_xor(ym, m));
    if (t == 0) ws[OFF_MAXY] = ym;
  }
}

// Full-stream certificate pass. Round-0/1 lesson: PARTIAL-row reads (256B or
// 128B of each 1KB row) run at ~1/4 to ~1/15 of streaming BW (channel
// interleave granule under-coverage). Reading ALL of x contiguously at
// ~6.4 TB/s (the poison fill measures 6.5 TB/s on this very path) costs
// ~64 us -- 3.5x faster than the "clever" quarter-read.
// Certificate is the FULL norm (exact, no subset slack):
//   cost(p,k) = xn + yn_k - 2 x.y_k >= (sqrt(xn) - maxy)^2.
// fp32 exp(-cost/0.1) == 0.0 exactly whenever cost > 10.41; we demand
// certified cost > 12.96 (thr = maxy*1.0001 + 0.01 + 3.6). xn ~ chi2(256):
// P(xn < 23.7) ~ 1e-60 -> zero suspects in practice; exact fallback kept.
// Layout: one wave per point; lane l reads float4 l of the point's 1KB row.
// Every wave instruction = one fully-consumed contiguous 1KB block; per
// round the whole grid covers a contiguous 8MB span.
__global__ __launch_bounds__(256) void main_kernel(const float* __restrict__ x,
    const int* __restrict__ bidx, float* __restrict__ ws) {
  __shared__ int hist[NG];
  int t = threadIdx.x, w = t >> 6, l = t & 63;
  int b = blockIdx.x, nb = gridDim.x;
  // --- per-graph node counts (grid-strided histogram) ---
  if (t < NG) hist[t] = 0;
  __syncthreads();
  for (int i = b * 256 + t; i < NNODES; i += nb * 256)
    atomicAdd(&hist[bidx[i] & 63], 1);
  __syncthreads();
  if (t < NG && hist[t] > 0) atomicAdd(&((int*)ws)[OFF_COUNTS + t], hist[t]);

  // --- full-norm certificate, wave-per-point, contiguous stream ---
  float maxy = ws[OFF_MAXY];
  float thr = fmaf(maxy, 1.0001f, 0.01f) + 3.6f;  // 3.6^2 = 12.96 > 10.41
  float thr2 = thr * thr;
  const float4* x4 = (const float4*)x;
  int gw = b * 4 + w, nw = nb * 4;
  int* nsusp = &((int*)ws)[OFF_NSUS];
  int* sus = &((int*)ws)[OFF_SUS];
  for (int p = gw; p < PTOT; p += nw) {
    float4 v = x4[(size_t)p * 64 + l];
    float e = dot4(v, v);
#pragma unroll
    for (int m = 1; m < 64; m <<= 1) e += __shfl_xor(e, m);
    if (l == 0) {
      // NaN in row -> comparison false -> suspect. Inf -> >1e30 -> suspect.
      bool safe = (e > thr2) && (e < 1e30f);
      if (!safe) {
        int slot = atomicAdd(nsusp, 1);
        if (slot < PTOT) sus[slot] = p;
      }
    }
  }
}

// Exact fallback: full reference-semantics Kmat row for each suspect point;
// nonzero rows are compacted for the solver. Grid-strided; near-free when empty.
__global__ __launch_bounds__(256) void suspect2_kernel(const float* __restrict__ x,
    const int* __restrict__ bidx, const float* __restrict__ cb,
    float* __restrict__ ws, int cap) {
  int tid = threadIdx.x;
  int wave = tid >> 6, lane = tid & 63;
  int nsus = ((int*)ws)[OFF_NSUS];
  if (nsus > PTOT) nsus = PTOT;
  const int* sus = &((int*)ws)[OFF_SUS];
  const float4* x4 = (const float4*)x;
  const float4* cb4 = (const float4*)cb;
  int gw = blockIdx.x * 4 + wave, nw = gridDim.x * 4;
  for (int si = gw; si < nsus; si += nw) {
    int p = sus[si];
    float4 xv = x4[(size_t)p * 64 + lane];
    float xn = dot4(xv, xv);
#pragma unroll
    for (int m = 1; m < 64; m <<= 1) xn += __shfl_xor(xn, m);
    float myk = 0.0f;
    for (int k = 0; k < KK; k++) {
      float4 c = cb4[k * 64 + lane];
      float d = dot4(xv, c);
#pragma unroll
      for (int m = 1; m < 64; m <<= 1) d += __shfl_xor(d, m);
      float cost = fmaxf(xn + ws[OFF_YN + k] - 2.0f * d, 0.0f);
      float km = __expf(cost * (-1.0f / EPSV));
      if (!(km <= 1.0f)) km = STABV;  // NaN -> STAB, per reference
      if (lane == k) myk = km;
    }
    unsigned long long nz = __ballot(myk != 0.0f);
    if (nz != 0ull) {
      int slot = 0;
      if (lane == 0) slot = atomicAdd(&((int*)ws)[OFF_NNZ], 1);
      slot = __shfl(slot, 0);
      if (slot < cap) {
        (ws + OFF_KROWS)[(size_t)slot * 64 + lane] = myk;
        if (lane == 0) ((int*)ws)[OFF_ROWSEG + slot] = bidx[p >> 3];
      }
    }
  }
}

// Sinkhorn over compacted rows + epilogue. Skips the 20-iter loop when the
// compact set is empty (device-side branch; launch sequence is unchanged).
__global__ __launch_bounds__(256) void solve_kernel(float* __restrict__ ws,
                                                    float* __restrict__ out, int cap) {
  __shared__ float vsh[NG * KK];
  __shared__ float ash[NG * KK];
  __shared__ float tot[NG];
  __shared__ float ainv[NG];
  int tid = threadIdx.x;
  int wave = tid >> 6, lane = tid & 63;
  int nnz = ((int*)ws)[OFF_NNZ];
  if (nnz > cap) nnz = cap;
  const float* krows = ws + OFF_KROWS;
  const int* rowseg = &((int*)ws)[OFF_ROWSEG];
  const int* counts = &((int*)ws)[OFF_COUNTS];
  float* uc = ws + OFF_UC;

  if (tid < NG) ainv[tid] = 1.0f / fmaxf((float)(counts[tid] * DIST), 1.0f);
  for (int i = tid; i < NG * KK; i += 256) { vsh[i] = 1.0f; ash[i] = 0.0f; }
  __syncthreads();

  if (nnz > 0) {
    for (int it = 0; it < NITERS; it++) {
      for (int i = tid; i < NG * KK; i += 256) ash[i] = 0.0f;
      __syncthreads();
      for (int r = wave; r < nnz; r += 4) {
        int g = rowseg[r];
        float kw = krows[(size_t)r * 64 + lane];
        float kv = kw * vsh[(g << 6) | lane];
#pragma unroll
        for (int m = 1; m < 64; m <<= 1) kv += __shfl_xor(kv, m);
        float u = ainv[g] / fmaxf(kv, STABV);
        if (it == NITERS - 1 && lane == 0) uc[r] = u;
        atomicAdd(&ash[(g << 6) | lane], kw * u);
      }
      __syncthreads();
      for (int i = tid; i < NG * KK; i += 256)
        vsh[i] = (1.0f / KK) / fmaxf(ash[i], STABV);
      __syncthreads();
    }
    for (int i = tid; i < NG * KK; i += 256) ash[i] = 0.0f;
    __syncthreads();
    for (int r = wave; r < nnz; r += 4) {
      int g = rowseg[r];
      float kw = krows[(size_t)r * 64 + lane];
      float u = fminf(fmaxf(uc[r], STABV), CMAXV);
      atomicAdd(&ash[(g << 6) | lane], kw * u);
    }
    __syncthreads();
  }

  for (int i = tid; i < NG * KK; i += 256) {
    float vv = fminf(fmaxf(vsh[i], STABV), CMAXV);
    ash[i] = ash[i] * vv;
  }
  __syncthreads();
  if (tid < NG) {
    float s = 0.0f;
    for (int k = 0; k < KK; k++) s += ash[(tid << 6) + k];
    tot[tid] = s;
  }
  __syncthreads();
  for (int i = tid; i < NG * KK; i += 256) {
    int g = i >> 6;
    float val;
    if (counts[g] == 0) val = 0.0f;
    else if (tot[g] > STABV) val = ash[i] / fmaxf(tot[g], STABV);
    else val = 1.0f / KK;
    out[i] = val;
  }
}

extern "C" void kernel_launch(void* const* d_in, const int* in_sizes, int n_in,
                              void* d_out, int out_size, void* d_ws, size_t ws_size,
                              hipStream_t stream) {
  const float* x = (const float*)d_in[0];      // [50000,8,256] f32
  const int* bidx = (const int*)d_in[1];       // [50000] int32
  const float* cb = (const float*)d_in[2];     // [64,256] f32
  float* ws = (float*)d_ws;
  float* out = (float*)d_out;

  long cap_l = ((long)(ws_size / 4) - OFF_KROWS) / 64;
  if (cap_l < 0) cap_l = 0;
  if (cap_l > PTOT) cap_l = PTOT;
  int cap = (int)cap_l;

  init_kernel<<<1, 256, 0, stream>>>(cb, ws);
  main_kernel<<<2048, 256, 0, stream>>>(x, bidx, ws);
  suspect2_kernel<<<64, 256, 0, stream>>>(x, bidx, cb, ws, cap);
  solve_kernel<<<1, 256, 0, stream>>>(ws, out, cap);
}

// Round 4
// 481.379 us; speedup vs baseline: 1.1278x; 1.1162x over previous
//
#include <hip/hip_runtime.h>

#define NG 64
#define KK 64
#define DIST 8
#define NNODES 50000
#define PTOT (NNODES*DIST)   // 400000 flattened rows
#define EPSV 0.1f
#define NITERS 20
#define STABV 1e-8f
#define CMAXV 1e6f

// ws layout (float-element offsets). ws is poisoned 0xAA before every call;
// everything below is written before it is read.
#define OFF_COUNTS 0                    // 64 i32
#define OFF_NNZ 64                      // 1 i32
#define OFF_NSUS 65                     // 1 i32
#define OFF_MAXY 66                     // 1 f32
#define OFF_YN 128                      // 64 f32
#define OFF_SUS 192                     // PTOT i32
#define OFF_ROWSEG (OFF_SUS + PTOT)     // PTOT i32
#define OFF_UC (OFF_ROWSEG + PTOT)      // PTOT f32
#define OFF_KROWS (OFF_UC + PTOT)       // cap*64 f32

__device__ __forceinline__ float dot4(float4 a, float4 b) {
  return fmaf(a.x, b.x, fmaf(a.y, b.y, fmaf(a.z, b.z, a.w * b.w)));
}

// Zero counters + codebook norms. Wave w, iter it exclusively owns k=4*it+w:
// coalesced cb read, butterfly reduce, no atomics.
__global__ __launch_bounds__(256) void init_kernel(const float* __restrict__ cb,
                                                   float* __restrict__ ws) {
  __shared__ float ynsh[KK];
  int t = threadIdx.x, w = t >> 6, l = t & 63;
  if (t < NG) ((int*)ws)[OFF_COUNTS + t] = 0;
  if (t == 0) { ((int*)ws)[OFF_NNZ] = 0; ((int*)ws)[OFF_NSUS] = 0; }
  const float4* cb4 = (const float4*)cb;
#pragma unroll
  for (int it = 0; it < 16; it++) {
    float4 c = cb4[it * 256 + t];
    float e = dot4(c, c);
#pragma unroll
    for (int m = 1; m < 64; m <<= 1) e += __shfl_xor(e, m);
    if (l == 0) ynsh[it * 4 + w] = e;
  }
  __syncthreads();
  if (t < KK) {
    float yn = ynsh[t];
    ws[OFF_YN + t] = yn;
    float ym = sqrtf(yn);
#pragma unroll
    for (int m = 1; m < 64; m <<= 1) ym = fmaxf(ym, __shfl_xor(ym, m));
    if (t == 0) ws[OFF_MAXY] = ym;
  }
}

// Fused counts + 64-elem subset-norm certificate (round-0 structure, 481.8us
// baseline) with ONE change: the channel-diagonal slot.
// Round-0 read bytes [0,256) of every 1KB row -> byte offsets == 0 mod 1024
// -> only granule indices == 0 mod 4 at 256B channel interleave -> 1/4-1/8
// of HBM channels -> ~440 GB/s effective. Fix: point p reads ITS slot p&3,
// i.e. bytes [256*(p&3), 256*(p&3)+256). Groups are laid out so p == q
// (mod 4) for 16-lane group q, so the per-lane float4 index is simply l:
// one wave instruction touches 4 x 256B chunks at stride 1280B = granule
// classes {0,1,2,3} mod 4 -> full channel coverage, traffic unchanged.
// Certificate (exact): S = sum over the 64-elem subset x_i^2 <= ||x||^2,
// so cost(p,k) >= (sqrt(S) - maxy)^2 when sqrt(S) > maxy. fp32
// exp(-cost/0.1) == 0.0 exactly whenever cost > 10.41; we demand certified
// cost > 12.96 (thr = maxy*1.0001 + 0.01 + 3.6). S ~ chi2(64):
// P(S < 23.8) ~ 1.2e-6 -> ~0 suspects; exact fallback keeps semantics.
__global__ __launch_bounds__(256) void main_kernel(const float* __restrict__ x,
    const int* __restrict__ bidx, float* __restrict__ ws) {
  __shared__ int hist[NG];
  int t = threadIdx.x, w = t >> 6, l = t & 63;
  int b = blockIdx.x;
  // --- per-graph node counts (this block's 40-node slice) ---
  if (t < NG) hist[t] = 0;
  __syncthreads();
  if (t < 40) atomicAdd(&hist[bidx[b * 40 + t] & 63], 1);
  __syncthreads();
  if (t < NG && hist[t] > 0) atomicAdd(&((int*)ws)[OFF_COUNTS + t], hist[t]);

  // --- subset-norm certificate, 320 points/block, 80/wave ---
  float maxy = ws[OFF_MAXY];
  float thr = fmaf(maxy, 1.0001f, 0.01f) + 3.6f;  // 3.6^2 = 12.96 > 10.41
  float thr2 = thr * thr;
  const float4* x4 = (const float4*)x;
  int q = l >> 4;              // 16-lane group q handles points == q (mod 4)
  int base = b * 320 + w * 80; // base % 4 == 0, so (base+q) & 3 == q
  int* nsusp = &((int*)ws)[OFF_NSUS];
  int* sus = &((int*)ws)[OFF_SUS];
#pragma unroll
  for (int o = 0; o < 5; o++) {
    int p0 = base + o * 16;
    // lane reads float4 index l = (q<<4) + r of its point's row: slot q.
    float4 v0 = x4[(size_t)(p0 + q) * 64 + l];
    float4 v1 = x4[(size_t)(p0 + 4 + q) * 64 + l];
    float4 v2 = x4[(size_t)(p0 + 8 + q) * 64 + l];
    float4 v3 = x4[(size_t)(p0 + 12 + q) * 64 + l];
    float s0 = dot4(v0, v0), s1 = dot4(v1, v1), s2 = dot4(v2, v2), s3 = dot4(v3, v3);
#pragma unroll
    for (int m = 1; m < 16; m <<= 1) {
      s0 += __shfl_xor(s0, m); s1 += __shfl_xor(s1, m);
      s2 += __shfl_xor(s2, m); s3 += __shfl_xor(s3, m);
    }
    if ((l & 15) == 0) {  // lane 16*q owns points p0+q, p0+4+q, p0+8+q, p0+12+q
      float ss[4] = {s0, s1, s2, s3};
#pragma unroll
      for (int i = 0; i < 4; i++) {
        // NaN in subset -> comparison false -> suspect. Inf -> >1e30 -> suspect.
        bool safe = (ss[i] > thr2) && (ss[i] < 1e30f);
        if (!safe) {
          int slot = atomicAdd(nsusp, 1);
          if (slot < PTOT) sus[slot] = p0 + 4 * i + q;
        }
      }
    }
  }
}

// Exact fallback: full reference-semantics Kmat row for each suspect point;
// nonzero rows are compacted for the solver. Grid-strided; near-free when empty.
__global__ __launch_bounds__(256) void suspect2_kernel(const float* __restrict__ x,
    const int* __restrict__ bidx, const float* __restrict__ cb,
    float* __restrict__ ws, int cap) {
  int tid = threadIdx.x;
  int wave = tid >> 6, lane = tid & 63;
  int nsus = ((int*)ws)[OFF_NSUS];
  if (nsus > PTOT) nsus = PTOT;
  const int* sus = &((int*)ws)[OFF_SUS];
  const float4* x4 = (const float4*)x;
  const float4* cb4 = (const float4*)cb;
  int gw = blockIdx.x * 4 + wave, nw = gridDim.x * 4;
  for (int si = gw; si < nsus; si += nw) {
    int p = sus[si];
    float4 xv = x4[(size_t)p * 64 + lane];
    float xn = dot4(xv, xv);
#pragma unroll
    for (int m = 1; m < 64; m <<= 1) xn += __shfl_xor(xn, m);
    float myk = 0.0f;
    for (int k = 0; k < KK; k++) {
      float4 c = cb4[k * 64 + lane];
      float d = dot4(xv, c);
#pragma unroll
      for (int m = 1; m < 64; m <<= 1) d += __shfl_xor(d, m);
      float cost = fmaxf(xn + ws[OFF_YN + k] - 2.0f * d, 0.0f);
      float km = __expf(cost * (-1.0f / EPSV));
      if (!(km <= 1.0f)) km = STABV;  // NaN -> STAB, per reference
      if (lane == k) myk = km;
    }
    unsigned long long nz = __ballot(myk != 0.0f);
    if (nz != 0ull) {
      int slot = 0;
      if (lane == 0) slot = atomicAdd(&((int*)ws)[OFF_NNZ], 1);
      slot = __shfl(slot, 0);
      if (slot < cap) {
        (ws + OFF_KROWS)[(size_t)slot * 64 + lane] = myk;
        if (lane == 0) ((int*)ws)[OFF_ROWSEG + slot] = bidx[p >> 3];
      }
    }
  }
}

// Sinkhorn over compacted rows + epilogue. Skips the 20-iter loop when the
// compact set is empty (device-side branch; launch sequence is unchanged).
__global__ __launch_bounds__(256) void solve_kernel(float* __restrict__ ws,
                                                    float* __restrict__ out, int cap) {
  __shared__ float vsh[NG * KK];
  __shared__ float ash[NG * KK];
  __shared__ float tot[NG];
  __shared__ float ainv[NG];
  int tid = threadIdx.x;
  int wave = tid >> 6, lane = tid & 63;
  int nnz = ((int*)ws)[OFF_NNZ];
  if (nnz > cap) nnz = cap;
  const float* krows = ws + OFF_KROWS;
  const int* rowseg = &((int*)ws)[OFF_ROWSEG];
  const int* counts = &((int*)ws)[OFF_COUNTS];
  float* uc = ws + OFF_UC;

  if (tid < NG) ainv[tid] = 1.0f / fmaxf((float)(counts[tid] * DIST), 1.0f);
  for (int i = tid; i < NG * KK; i += 256) { vsh[i] = 1.0f; ash[i] = 0.0f; }
  __syncthreads();

  if (nnz > 0) {
    for (int it = 0; it < NITERS; it++) {
      for (int i = tid; i < NG * KK; i += 256) ash[i] = 0.0f;
      __syncthreads();
      for (int r = wave; r < nnz; r += 4) {
        int g = rowseg[r];
        float kw = krows[(size_t)r * 64 + lane];
        float kv = kw * vsh[(g << 6) | lane];
#pragma unroll
        for (int m = 1; m < 64; m <<= 1) kv += __shfl_xor(kv, m);
        float u = ainv[g] / fmaxf(kv, STABV);
        if (it == NITERS - 1 && lane == 0) uc[r] = u;
        atomicAdd(&ash[(g << 6) | lane], kw * u);
      }
      __syncthreads();
      for (int i = tid; i < NG * KK; i += 256)
        vsh[i] = (1.0f / KK) / fmaxf(ash[i], STABV);
      __syncthreads();
    }
    for (int i = tid; i < NG * KK; i += 256) ash[i] = 0.0f;
    __syncthreads();
    for (int r = wave; r < nnz; r += 4) {
      int g = rowseg[r];
      float kw = krows[(size_t)r * 64 + lane];
      float u = fminf(fmaxf(uc[r], STABV), CMAXV);
      atomicAdd(&ash[(g << 6) | lane], kw * u);
    }
    __syncthreads();
  }

  for (int i = tid; i < NG * KK; i += 256) {
    float vv = fminf(fmaxf(vsh[i], STABV), CMAXV);
    ash[i] = ash[i] * vv;
  }
  __syncthreads();
  if (tid < NG) {
    float s = 0.0f;
    for (int k = 0; k < KK; k++) s += ash[(tid << 6) + k];
    tot[tid] = s;
  }
  __syncthreads();
  for (int i = tid; i < NG * KK; i += 256) {
    int g = i >> 6;
    float val;
    if (counts[g] == 0) val = 0.0f;
    else if (tot[g] > STABV) val = ash[i] / fmaxf(tot[g], STABV);
    else val = 1.0f / KK;
    out[i] = val;
  }
}

extern "C" void kernel_launch(void* const* d_in, const int* in_sizes, int n_in,
                              void* d_out, int out_size, void* d_ws, size_t ws_size,
                              hipStream_t stream) {
  const float* x = (const float*)d_in[0];      // [50000,8,256] f32
  const int* bidx = (const int*)d_in[1];       // [50000] int32
  const float* cb = (const float*)d_in[2];     // [64,256] f32
  float* ws = (float*)d_ws;
  float* out = (float*)d_out;

  long cap_l = ((long)(ws_size / 4) - OFF_KROWS) / 64;
  if (cap_l < 0) cap_l = 0;
  if (cap_l > PTOT) cap_l = PTOT;
  int cap = (int)cap_l;

  init_kernel<<<1, 256, 0, stream>>>(cb, ws);
  main_kernel<<<NNODES / 40, 256, 0, stream>>>(x, bidx, ws);  // 1250 blocks
  suspect2_kernel<<<64, 256, 0, stream>>>(x, bidx, cb, ws, cap);
  solve_kernel<<<1, 256, 0, stream>>>(ws, out, cap);
}